// Round 3
// baseline (166.432 us; speedup 1.0000x reference)
//
#include <hip/hip_runtime.h>

// FFTPermuter: out_chunk[c][col] = x[8*col + ms[c]], ms = {0,4,2,6,1,5,3,7}
// (perm is a compile-time one-hot permutation; never read).
//
// R2: R0 (direct gather) and R1 (LDS transpose) both sat at ~40us / 2.4 TB/s
// -> access pattern was NOT the limiter. Both were one-shot kernels (one
// load-wait-store round per wave, no pipelining). This version:
//   - grid-stride loop, 4 iterations/thread, fully unrolled: iteration i+1's
//     loads overlap iteration i's stores (VMEM queue stays full)
//   - non-temporal loads+stores: both streams are touch-once, 128 MiB total
//     vs 32 MiB aggregate L2 -> skip retention churn
//   - no LDS, no barrier

typedef float v4f __attribute__((ext_vector_type(4)));

#define COLS_TOTAL  (8u * 512u * 512u)       // 2^21 column slots
#define NGROUPS     (COLS_TOTAL / 4)         // 524288 groups of 4 columns
#define BLOCK       256
#define GRID        512                      // 2 blocks/CU, 8 waves/CU
#define ITERS       (NGROUPS / (GRID * BLOCK))   // = 4

__global__ __launch_bounds__(BLOCK) void
FFTPermuter_2748779070248_kernel(const v4f* __restrict__ x4,
                                 v4f* __restrict__ out4) {
    const int stride = GRID * BLOCK;
    int g = blockIdx.x * BLOCK + threadIdx.x;

    const int ms[8] = {0, 4, 2, 6, 1, 5, 3, 7};   // 3-bit bit-reversal

#pragma unroll
    for (int it = 0; it < ITERS; ++it, g += stride) {
        // columns 4g..4g+3, all 8 phases: 8x contiguous float4
        // element (col 4g+q, phase p) = v[2q + p/4][p%4]
        v4f v[8];
#pragma unroll
        for (int m = 0; m < 8; ++m)
            v[m] = __builtin_nontemporal_load(&x4[(size_t)g * 8 + m]);

#pragma unroll
        for (int c = 0; c < 8; ++c) {
            const int p  = ms[c];
            const int hi = p >> 2, lo = p & 3;
            v4f o;
            o.x = v[0 + hi][lo];
            o.y = v[2 + hi][lo];
            o.z = v[4 + hi][lo];
            o.w = v[6 + hi][lo];
            __builtin_nontemporal_store(o, &out4[(size_t)c * (COLS_TOTAL / 4) + g]);
        }
    }
}

extern "C" void kernel_launch(void* const* d_in, const int* in_sizes, int n_in,
                              void* d_out, int out_size, void* d_ws, size_t ws_size,
                              hipStream_t stream) {
    const v4f* x4   = (const v4f*)d_in[0];   // x: [8,512,4096] fp32
    v4f*       out4 = (v4f*)d_out;           // 8 chunks of [8,512,512] fp32

    FFTPermuter_2748779070248_kernel<<<GRID, BLOCK, 0, stream>>>(x4, out4);
}

// Round 4
// 155.974 us; speedup vs baseline: 1.0670x; 1.0670x over previous
//
#include <hip/hip_runtime.h>

// FFTPermuter: out_chunk[c][col] = x[8*col + ms[c]], ms = {0,4,2,6,1,5,3,7}
// (perm is a compile-time one-hot permutation; never read).
//
// R0 (direct), R1 (LDS, fully coalesced), R2 (grid-stride) all pinned at
// 2.4-2.6 TB/s. Invariant across all three: every wave stored to all 8
// output streams (8 MiB apart). R3 isolates that variable: 8-wave blocks,
// LDS transpose as R1, but wave w writes ONLY chunk w — 4 KiB contiguous
// per wave, scalar (wave-uniform) stream base. One write stream per wave.

#define COLS_TOTAL  (8u * 512u * 512u)     // 2^21 column slots
#define TILE_COLS   1024
#define BLOCK       512                    // 8 waves = 8 chunks

__global__ __launch_bounds__(BLOCK) void
FFTPermuter_2748779070248_kernel(const float4* __restrict__ x4,
                                 float4* __restrict__ out4) {
    __shared__ __align__(16) float lds[8 * TILE_COLS];   // [phase][col], 32 KiB

    const int    tid   = threadIdx.x;
    const size_t tile  = blockIdx.x;          // 2048 tiles
    const size_t base4 = tile * 2048;         // 2048 float4 of input per tile

    // ---- phase 1: coalesced global load -> LDS transpose-scatter ----
    // (identical pattern to R1; 2-way bank aliasing = free)
#pragma unroll
    for (int k = 0; k < 4; ++k) {
        const int e4 = k * BLOCK + tid;       // float4 index in tile, 0..2047
        float4 v = x4[base4 + e4];
        const int col = e4 >> 1;              // 0..1023
        const int ph0 = (e4 & 1) * 4;         // phases 0-3 or 4-7
        lds[(ph0 + 0) * TILE_COLS + col] = v.x;
        lds[(ph0 + 1) * TILE_COLS + col] = v.y;
        lds[(ph0 + 2) * TILE_COLS + col] = v.z;
        lds[(ph0 + 3) * TILE_COLS + col] = v.w;
    }
    __syncthreads();

    // ---- phase 2: wave w drains chunk w only (single contiguous stream) ----
    const int w = tid >> 6;                   // wave id = chunk id, uniform
    const int l = tid & 63;                   // lane
    // p = 3-bit bit-reversal of w: {0,4,2,6,1,5,3,7}
    const int p = ((w & 1) << 2) | (w & 2) | ((w >> 2) & 1);

    const float4* src = (const float4*)&lds[p * TILE_COLS];
    const size_t  dst = (size_t)w * (COLS_TOTAL / 4) + tile * (TILE_COLS / 4);
#pragma unroll
    for (int j = 0; j < 4; ++j)               // 4 x 1 KiB, 4 KiB contiguous/wave
        out4[dst + j * 64 + l] = src[j * 64 + l];
}

extern "C" void kernel_launch(void* const* d_in, const int* in_sizes, int n_in,
                              void* d_out, int out_size, void* d_ws, size_t ws_size,
                              hipStream_t stream) {
    const float4* x4   = (const float4*)d_in[0];   // x: [8,512,4096] fp32
    float4*       out4 = (float4*)d_out;           // 8 chunks of [8,512,512] fp32

    const int grid = COLS_TOTAL / TILE_COLS;       // 2048 blocks
    FFTPermuter_2748779070248_kernel<<<grid, BLOCK, 0, stream>>>(x4, out4);
}

// Round 5
// 155.017 us; speedup vs baseline: 1.0736x; 1.0062x over previous
//
#include <hip/hip_runtime.h>

// FFTPermuter: out_chunk[c][col] = x[8*col + ms[c]], ms = {0,4,2,6,1,5,3,7}
// (perm is a compile-time one-hot permutation; never read).
//
// R0 (direct), R1 (LDS transpose), R2 (grid-stride+NT), R3 (wave-per-chunk
// stores) ALL pinned at 2.4-2.6 TB/s — access-pattern hypotheses eliminated.
// R4 tests memory-level parallelism: each thread owns TWO column-groups and
// issues all 16 global loads before any store (2x outstanding requests of
// every prior round), no NT (keep L3 hits), 1024x256 grid for ~20 waves/CU.

typedef float v4f __attribute__((ext_vector_type(4)));

#define COLS_TOTAL  (8u * 512u * 512u)       // 2^21 column slots
#define NGROUPS     (COLS_TOTAL / 4)         // 524288 groups of 4 columns
#define BLOCK       256
#define GRID        1024
#define NTHREADS    (GRID * BLOCK)           // 262144 -> 2 groups/thread

__global__ __launch_bounds__(BLOCK) void
FFTPermuter_2748779070248_kernel(const v4f* __restrict__ x4,
                                 v4f* __restrict__ out4) {
    const int t  = blockIdx.x * BLOCK + threadIdx.x;
    const int g0 = t;                         // group 0
    const int g1 = t + NTHREADS;              // group 1 (still lane-consecutive)

    // Issue ALL 16 loads before any store: 256 B of loads in flight/thread.
    v4f v0[8], v1[8];
#pragma unroll
    for (int m = 0; m < 8; ++m) v0[m] = x4[(size_t)g0 * 8 + m];
#pragma unroll
    for (int m = 0; m < 8; ++m) v1[m] = x4[(size_t)g1 * 8 + m];

    const int ms[8] = {0, 4, 2, 6, 1, 5, 3, 7};   // 3-bit bit-reversal

#pragma unroll
    for (int c = 0; c < 8; ++c) {
        const int p  = ms[c];
        const int hi = p >> 2, lo = p & 3;
        const size_t cb = (size_t)c * (COLS_TOTAL / 4);
        v4f o;
        o.x = v0[0 + hi][lo];
        o.y = v0[2 + hi][lo];
        o.z = v0[4 + hi][lo];
        o.w = v0[6 + hi][lo];
        out4[cb + g0] = o;
        v4f q;
        q.x = v1[0 + hi][lo];
        q.y = v1[2 + hi][lo];
        q.z = v1[4 + hi][lo];
        q.w = v1[6 + hi][lo];
        out4[cb + g1] = q;
    }
}

extern "C" void kernel_launch(void* const* d_in, const int* in_sizes, int n_in,
                              void* d_out, int out_size, void* d_ws, size_t ws_size,
                              hipStream_t stream) {
    const v4f* x4   = (const v4f*)d_in[0];   // x: [8,512,4096] fp32
    v4f*       out4 = (v4f*)d_out;           // 8 chunks of [8,512,512] fp32

    FFTPermuter_2748779070248_kernel<<<GRID, BLOCK, 0, stream>>>(x4, out4);
}

// Round 6
// 153.865 us; speedup vs baseline: 1.0817x; 1.0075x over previous
//
#include <hip/hip_runtime.h>

// FFTPermuter: out_chunk[c][col] = x[8*col + ms[c]], ms = {0,4,2,6,1,5,3,7}
// (perm is a compile-time one-hot permutation; never read).
//
// R0-R4: five structures (direct, LDS transpose, grid-stride+NT, wave-per-
// chunk, 2x MLP) all pinned at 2.4-2.6 TB/s across 14-53% occupancy.
// R5 isolates the last cache-side variable: the harness poison-fills the
// entire 256 MiB L3 right before us, and our cached stores evict x while we
// read it (FETCH stuck at 33 MB = half of x). This round: R4 verbatim but
// NON-TEMPORAL STORES ONLY (loads stay cached) — writes stream to HBM
// without L2/L3 write-allocate, cache hierarchy reserved for the read side.

typedef float v4f __attribute__((ext_vector_type(4)));

#define COLS_TOTAL  (8u * 512u * 512u)       // 2^21 column slots
#define NGROUPS     (COLS_TOTAL / 4)         // 524288 groups of 4 columns
#define BLOCK       256
#define GRID        1024
#define NTHREADS    (GRID * BLOCK)           // 262144 -> 2 groups/thread

__global__ __launch_bounds__(BLOCK) void
FFTPermuter_2748779070248_kernel(const v4f* __restrict__ x4,
                                 v4f* __restrict__ out4) {
    const int t  = blockIdx.x * BLOCK + threadIdx.x;
    const int g0 = t;                         // group 0
    const int g1 = t + NTHREADS;              // group 1 (still lane-consecutive)

    // Issue ALL 16 loads before any store (cached: keep L3 hits on x).
    v4f v0[8], v1[8];
#pragma unroll
    for (int m = 0; m < 8; ++m) v0[m] = x4[(size_t)g0 * 8 + m];
#pragma unroll
    for (int m = 0; m < 8; ++m) v1[m] = x4[(size_t)g1 * 8 + m];

    const int ms[8] = {0, 4, 2, 6, 1, 5, 3, 7};   // 3-bit bit-reversal

#pragma unroll
    for (int c = 0; c < 8; ++c) {
        const int p  = ms[c];
        const int hi = p >> 2, lo = p & 3;
        const size_t cb = (size_t)c * (COLS_TOTAL / 4);
        v4f o;
        o.x = v0[0 + hi][lo];
        o.y = v0[2 + hi][lo];
        o.z = v0[4 + hi][lo];
        o.w = v0[6 + hi][lo];
        __builtin_nontemporal_store(o, &out4[cb + g0]);
        v4f q;
        q.x = v1[0 + hi][lo];
        q.y = v1[2 + hi][lo];
        q.z = v1[4 + hi][lo];
        q.w = v1[6 + hi][lo];
        __builtin_nontemporal_store(q, &out4[cb + g1]);
    }
}

extern "C" void kernel_launch(void* const* d_in, const int* in_sizes, int n_in,
                              void* d_out, int out_size, void* d_ws, size_t ws_size,
                              hipStream_t stream) {
    const v4f* x4   = (const v4f*)d_in[0];   // x: [8,512,4096] fp32
    v4f*       out4 = (v4f*)d_out;           // 8 chunks of [8,512,512] fp32

    FFTPermuter_2748779070248_kernel<<<GRID, BLOCK, 0, stream>>>(x4, out4);
}